// Round 12
// baseline (169.479 us; speedup 1.0000x reference)
//
#include <hip/hip_runtime.h>
#include <hip/hip_bf16.h>

// B=4, C=64, H=W=64, D=4, CQ=8. N=H*W=4096, f_qk=32, f_v=256. I/O fp32.
// R12 = R11 with flash XCD-pinning: group g=(b,cvh) -> blk&7 so each of the
// 8 groups (V-half 1.05MB + K/Q 0.5MB < 4MB) stays in one XCD's L2.
// R11 analysis: flash streams 604MB of V at ~10TB/s = L3 ceiling; pinning
// turns V re-reads into per-XCD L2 hits (~4.3TB/s/XCD, 8 XCDs in parallel).
// Also: packed bf16 conversion (v_cvt_pk_bf16_f32) halves the P-pack VALU.
// qkv unchanged from R11 (paired accumulators, LDS transpose, coalesced out).
#define CH 64
#define NN 4096
#define SS 16384

typedef __attribute__((ext_vector_type(8))) short bf16x8;
typedef __attribute__((ext_vector_type(4))) float f32x4;

// ws layout (ushort elems): Qb (B,N,32) | Kb (B,N,32) |
// Vt [b][sup:32][cv:256][slot:144] (128 data slots + 16 pad)
#define QB_OFF 0
#define KB_OFF 524288
#define VT_OFF 1048576

static __device__ __forceinline__ ushort bfbits(float x) {
    __hip_bfloat16 h = __float2bfloat16(x);
    return *(ushort*)&h;
}

static __device__ __forceinline__ void gld_lds16(const ushort* g, ushort* l) {
    __builtin_amdgcn_global_load_lds(
        (const __attribute__((address_space(1))) void*)g,
        (__attribute__((address_space(3))) void*)l, 16, 0, 0);
}

// ---------------- qkv ---------------- (unchanged from R11)
// grid 512 = (b, sup in [0,32), og in [0,4)). 256 threads = (nl = tid>>2, d).
__global__ __launch_bounds__(256) void qkv_kernel(
    const float* __restrict__ x,
    const float* __restrict__ Wq, const float* __restrict__ bq,
    const float* __restrict__ Wk, const float* __restrict__ bk,
    const float* __restrict__ Wv, const float* __restrict__ bv,
    ushort* __restrict__ qb, ushort* __restrict__ kb, ushort* __restrict__ vt)
{
    __shared__ __align__(16) ushort Tqk[128 * 40];  // [n_loc][f], q or k
    __shared__ __align__(16) ushort Tv[80 * 144];   // [cv_loc][slot]

    const int blk = blockIdx.x;
    const int b = blk >> 7, sup = (blk >> 2) & 31, og = blk & 3;
    const int tid = threadIdx.x;
    const int nl = tid >> 2, d = tid & 3;

    const int vcnt = (og < 2) ? 12 : 20;
    const int vo0 = (og == 0) ? 0 : (og == 1) ? 12 : (og == 2) ? 24 : 44;

    const float* xb = x + (size_t)b * CH * SS + sup * 512;

    for (int t = 0; t < 2; ++t) {
        const float* xp = xb + t * 256 + tid;
        float xr[CH];
#pragma unroll
        for (int c = 0; c < CH; ++c) xr[c] = xp[(size_t)c * SS];

        const int slot = 32 * (nl >> 4) + 8 * ((nl >> 2) & 3) + 4 * t + (nl & 3);

        if (og < 2) {
            const float* Wqk = (og == 0) ? Wq : Wk;
            const float* bqk = (og == 0) ? bq : bk;
            ushort* trow = &Tqk[(t * 64 + nl) * 40 + d];
#pragma unroll
            for (int o = 0; o < 8; o += 2) {
                float a0 = bqk[o], a1 = bqk[o + 1];
#pragma unroll
                for (int c = 0; c < CH; ++c) {
                    a0 = fmaf(Wqk[o * CH + c],       xr[c], a0);
                    a1 = fmaf(Wqk[(o + 1) * CH + c], xr[c], a1);
                }
                trow[o * 4]       = bfbits(a0);
                trow[(o + 1) * 4] = bfbits(a1);
            }
        }
        ushort* vcol = &Tv[d * 144 + slot];
        const float* Wvb = Wv + vo0 * CH;
        const float* bvb = bv + vo0;
        if (og < 2) {
#pragma unroll
            for (int j = 0; j < 12; j += 2) {
                float a0 = bvb[j], a1 = bvb[j + 1];
#pragma unroll
                for (int c = 0; c < CH; ++c) {
                    a0 = fmaf(Wvb[j * CH + c],       xr[c], a0);
                    a1 = fmaf(Wvb[(j + 1) * CH + c], xr[c], a1);
                }
                vcol[(j * 4) * 144]       = bfbits(a0);
                vcol[((j + 1) * 4) * 144] = bfbits(a1);
            }
        } else {
#pragma unroll
            for (int j = 0; j < 20; j += 2) {
                float a0 = bvb[j], a1 = bvb[j + 1];
#pragma unroll
                for (int c = 0; c < CH; ++c) {
                    a0 = fmaf(Wvb[j * CH + c],       xr[c], a0);
                    a1 = fmaf(Wvb[(j + 1) * CH + c], xr[c], a1);
                }
                vcol[(j * 4) * 144]       = bfbits(a0);
                vcol[((j + 1) * 4) * 144] = bfbits(a1);
            }
        }
    }
    __syncthreads();

    if (og < 2) {
        ushort* dst = (og == 0 ? qb : kb);
#pragma unroll
        for (int jj = 0; jj < 2; ++jj) {
            int idx = jj * 256 + tid;
            int row = idx >> 2, seg = idx & 3;
            *(uint4*)(dst + ((size_t)(b * NN + sup * 128 + row)) * 32 + seg * 8)
                = *(const uint4*)&Tqk[row * 40 + seg * 8];
        }
    }
    const int nchunks = vcnt * 64;
    ushort* vout = vt + ((size_t)((b * 32 + sup) * 256 + vo0 * 4)) * 144;
#pragma unroll
    for (int j = 0; j < 5; ++j) {
        int idx = j * 256 + tid;
        if (idx < nchunks) {
            int row = idx >> 4, seg = idx & 15;
            *(uint4*)(vout + (size_t)row * 144 + seg * 8)
                = *(const uint4*)&Tv[row * 144 + seg * 8];
        }
    }
}

// ---------------- flash ----------------
// grid 512. XCD-pinned decode: group g = blk & 7 = (b<<1)|cvh (one group per
// XCD via the %8 round-robin dispatch heuristic); r-tile = blk >> 3.
__global__ __launch_bounds__(256, 2) void flash_kernel(
    const ushort* __restrict__ qb, const ushort* __restrict__ kb,
    const ushort* __restrict__ vt, const float* __restrict__ x3d,
    const float* __restrict__ gptr, float* __restrict__ out)
{
    __shared__ __align__(16) ushort Vls[2][128 * 144];  // [cv'][slot], dbuf
    __shared__ float lbuf[4 * 4 * 16];

    const int tid = threadIdx.x;
    const int g   = blockIdx.x & 7;
    const int b   = g >> 1;
    const int cvh = g & 1;
    const int r0  = (blockIdx.x >> 3) << 6;
    const int w = tid >> 6, lane = tid & 63, q = lane >> 4, l15 = lane & 15;

    // Q B-frags (16x16x32): B[f=8q+j][r=16rt+l15]
    bf16x8 Qf[4];
#pragma unroll
    for (int rt = 0; rt < 4; ++rt)
        Qf[rt] = *(const bf16x8*)(qb + (size_t)(b * NN + r0 + 16 * rt + l15) * 32 + 8 * q);

    f32x4 acc[8][4];
#pragma unroll
    for (int i = 0; i < 8; ++i)
#pragma unroll
        for (int j = 0; j < 4; ++j) acc[i][j] = (f32x4){0.f, 0.f, 0.f, 0.f};
    float l_acc[4] = {0.f, 0.f, 0.f, 0.f};

    // K rows for wave w, tile mt: kb[(mt*64 + 16w + l15)*32 + 8q]
    const ushort* kgl = kb + (size_t)b * NN * 32 + (16 * w + l15) * 32 + 8 * q;

    // V stream: block's 128-cv half of each sup = 128*144 ushorts contiguous
    const ushort* vgl = vt + ((size_t)(b * 32) * 256 + 128 * cvh) * 144;

    // async stage pair 0 -> buf 0 (wave-uniform base + lane*16: valid DMA)
#pragma unroll
    for (int i = 0; i < 9; ++i)
        gld_lds16(vgl + (size_t)(i * 256 + tid) * 8,
                  (ushort*)Vls[0] + (i * 256 + tid) * 8);

    bf16x8 Kn0 = *(const bf16x8*)(kgl);
    bf16x8 Kn1 = *(const bf16x8*)(kgl + 2048);

    for (int pt = 0; pt < 32; ++pt) {
        __syncthreads();   // vmcnt drained: buf[pt&1] DMA landed; buf[pt^1] readers done
        if (pt < 31) {     // async prefetch pair pt+1 into the other buffer
            const ushort* src = vgl + (size_t)(pt + 1) * 36864;
            ushort* dst = (ushort*)Vls[(pt + 1) & 1];
#pragma unroll
            for (int i = 0; i < 9; ++i)
                gld_lds16(src + (size_t)(i * 256 + tid) * 8, dst + (i * 256 + tid) * 8);
        }
        bf16x8 Ka0 = Kn0, Ka1 = Kn1;   // loaded last iter, resolved by barrier
        if (pt < 31) {
            Kn0 = *(const bf16x8*)(kgl + (size_t)(2 * pt + 2) * 2048);
            Kn1 = *(const bf16x8*)(kgl + (size_t)(2 * pt + 3) * 2048);
        }

        // S^T slices: D[m=4q+reg][r=16rt+l15] for tiles 0,1 of the pair
        f32x4 S0[4], S1[4];
#pragma unroll
        for (int rt = 0; rt < 4; ++rt)
            S0[rt] = __builtin_amdgcn_mfma_f32_16x16x32_bf16(
                Ka0, Qf[rt], (f32x4){0.f, 0.f, 0.f, 0.f}, 0, 0, 0);
#pragma unroll
        for (int rt = 0; rt < 4; ++rt)
            S1[rt] = __builtin_amdgcn_mfma_f32_16x16x32_bf16(
                Ka1, Qf[rt], (f32x4){0.f, 0.f, 0.f, 0.f}, 0, 0, 0);

        // exp (no max-sub: |s| <~ 9); packed bf16 cvt; concat pair C-layouts
        bf16x8 Pb[4];
#pragma unroll
        for (int rt = 0; rt < 4; ++rt) {
            float e0 = __expf(S0[rt][0]), e1 = __expf(S0[rt][1]);
            float e2 = __expf(S0[rt][2]), e3 = __expf(S0[rt][3]);
            float f0 = __expf(S1[rt][0]), f1 = __expf(S1[rt][1]);
            float f2 = __expf(S1[rt][2]), f3 = __expf(S1[rt][3]);
            l_acc[rt] += ((e0 + e1) + (e2 + e3)) + ((f0 + f1) + (f2 + f3));
            union { bf16x8 v; __hip_bfloat162 h[4]; } u;
            u.h[0] = __float22bfloat162_rn(make_float2(e0, e1));
            u.h[1] = __float22bfloat162_rn(make_float2(e2, e3));
            u.h[2] = __float22bfloat162_rn(make_float2(f0, f1));
            u.h[3] = __float22bfloat162_rn(make_float2(f2, f3));
            Pb[rt] = u.v;
        }

        // PV: A[cv=16cvt+l15][k=8q+j] = one ds_read_b128 (slots 32w+8q..+7)
        const ushort* vb = Vls[pt & 1] + 32 * w + 8 * q;
#pragma unroll
        for (int cvt = 0; cvt < 8; ++cvt) {
            bf16x8 Va = *(const bf16x8*)(vb + (16 * cvt + l15) * 144);
#pragma unroll
            for (int rt = 0; rt < 4; ++rt)
                acc[cvt][rt] = __builtin_amdgcn_mfma_f32_16x16x32_bf16(
                    Va, Pb[rt], acc[cvt][rt], 0, 0, 0);
        }
    }

    // l: reduce over quads (shfl) then across 4 waves (lbuf)
#pragma unroll
    for (int rt = 0; rt < 4; ++rt) {
        float v = l_acc[rt];
        v += __shfl_xor(v, 16);
        v += __shfl_xor(v, 32);
        if (lane < 16) lbuf[(w * 4 + rt) * 16 + lane] = v;
    }
    __syncthreads();
    // this thread's epilogue rows are r = 16w + l15 (rt = w)
    const float linv = 1.f / (lbuf[(0 + w) * 16 + l15] + lbuf[(4 + w) * 16 + l15] +
                              lbuf[(8 + w) * 16 + l15] + lbuf[(12 + w) * 16 + l15]);
    const float gl = gptr[0] * linv;

    // cross-wave O reduction in 8 cvt chunks; Obuf aliases Vls[0]
    f32x4* Obuf = (f32x4*)&Vls[0][0];
#pragma unroll
    for (int cvt = 0; cvt < 8; ++cvt) {
        __syncthreads();
#pragma unroll
        for (int rt = 0; rt < 4; ++rt)
            Obuf[(w * 64 + lane) * 5 + rt] = acc[cvt][rt];
        __syncthreads();
        f32x4 o = Obuf[lane * 5 + w];
        o += Obuf[(64 + lane) * 5 + w];
        o += Obuf[(128 + lane) * 5 + w];
        o += Obuf[(192 + lane) * 5 + w];
        // cv = 128cvh + 16cvt + 4q + reg -> c = 32cvh + 4cvt + q, d = reg
        size_t addr = ((size_t)(b * CH + 32 * cvh + 4 * cvt + q) * NN
                       + (r0 + 16 * w + l15)) * 4;
        float4 xr = *(const float4*)(x3d + addr);
        float4 res;
        res.x = fmaf(gl, o[0], xr.x);
        res.y = fmaf(gl, o[1], xr.y);
        res.z = fmaf(gl, o[2], xr.z);
        res.w = fmaf(gl, o[3], xr.w);
        *(float4*)(out + addr) = res;
    }
}

extern "C" void kernel_launch(void* const* d_in, const int* in_sizes, int n_in,
                              void* d_out, int out_size, void* d_ws, size_t ws_size,
                              hipStream_t stream)
{
    const float* x2d = (const float*)d_in[0];
    const float* x3d = (const float*)d_in[1];
    const float* Wq  = (const float*)d_in[2];
    const float* bq  = (const float*)d_in[3];
    const float* Wk  = (const float*)d_in[4];
    const float* bk  = (const float*)d_in[5];
    const float* Wv  = (const float*)d_in[6];
    const float* bv  = (const float*)d_in[7];
    const float* gma = (const float*)d_in[8];

    ushort* wsb = (ushort*)d_ws;

    qkv_kernel<<<512, 256, 0, stream>>>(x2d, Wq, bq, Wk, bk, Wv, bv,
                                        wsb + QB_OFF, wsb + KB_OFF, wsb + VT_OFF);
    flash_kernel<<<512, 256, 0, stream>>>(wsb + QB_OFF, wsb + KB_OFF, wsb + VT_OFF,
                                          x3d, gma, (float*)d_out);
}